// Round 1
// baseline (152.799 us; speedup 1.0000x reference)
//
#include <hip/hip_runtime.h>

// Problem constants (from setup_inputs): disp [8,384,1280,1] f32
#define BATCH 8
#define HH 384
#define WW 1280
#define TW 32           // tile width  (threads x)
#define TH 8            // tile height (threads y)
#define LW (TW + 4)     // 36: tile + 2-halo each side
#define LH (TH + 4)     // 12

// ---------------------------------------------------------------------------
// Per-batch prep: K1 = K_scale @ K0, K1^{-1} (double adjugate), fxb = K1[0,0]*b
// Layout in ws: per batch 12 floats: Ki[0..8], fxb, pad, pad
// ---------------------------------------------------------------------------
__global__ void prep_kernel(const float* __restrict__ K0,
                            const float* __restrict__ baseline,
                            const int* __restrict__ h0p,
                            const int* __restrict__ w0p,
                            float* __restrict__ cst) {
  int b = threadIdx.x;
  if (b >= BATCH) return;
  float w0 = (float)w0p[0];
  float h0 = (float)h0p[0];
  float rw = (float)WW / w0;
  float rh = (float)HH / h0;
  float s02 = 0.5f * (rw - 1.0f);
  float s12 = 0.5f * (rh - 1.0f);
  const float* K = K0 + b * 9;
  float k0 = rw * K[0] + s02 * K[6];
  float k1 = rw * K[1] + s02 * K[7];
  float k2 = rw * K[2] + s02 * K[8];
  float k3 = rh * K[3] + s12 * K[6];
  float k4 = rh * K[4] + s12 * K[7];
  float k5 = rh * K[5] + s12 * K[8];
  float k6 = K[6], k7 = K[7], k8 = K[8];
  // 3x3 inverse via adjugate in double (jnp.linalg.inv equivalent to ulps)
  double a = k0, bb = k1, c = k2, d = k3, e = k4, f = k5, g = k6, h = k7, i = k8;
  double cA = e * i - f * h;
  double cB = -(d * i - f * g);
  double cC = d * h - e * g;
  double det = a * cA + bb * cB + c * cC;
  double idet = 1.0 / det;
  float* o = cst + b * 12;
  o[0] = (float)(cA * idet);
  o[1] = (float)(-(bb * i - c * h) * idet);
  o[2] = (float)((bb * f - c * e) * idet);
  o[3] = (float)(cB * idet);
  o[4] = (float)((a * i - c * g) * idet);
  o[5] = (float)(-(a * f - c * d) * idet);
  o[6] = (float)(cC * idet);
  o[7] = (float)(-(a * h - bb * g) * idet);
  o[8] = (float)((a * e - bb * d) * idet);
  o[9] = k0 * baseline[b];
}

// ---------------------------------------------------------------------------
// Fused: depth + xyz staging (LDS, float4 with depth in .w) + 5x5 windowed
// covariance + closed-form 3x3 eigen + plane mask.
// ---------------------------------------------------------------------------
__global__ __launch_bounds__(256) void tmap_fused(
    const float* __restrict__ disp,
    const float* __restrict__ cst,
    float* __restrict__ out_depth,
    float* __restrict__ out_mask) {
  __shared__ float tile[LH][LW][4];  // x, y, z, depth

  const int b = blockIdx.z;
  const float* C = cst + b * 12;
  const float Ki00 = C[0], Ki01 = C[1], Ki02 = C[2];
  const float Ki10 = C[3], Ki11 = C[4], Ki12 = C[5];
  const float Ki20 = C[6], Ki21 = C[7], Ki22 = C[8];
  const float fxb = C[9];

  const int j0 = blockIdx.x * TW;
  const int i0 = blockIdx.y * TH;
  const int tid = threadIdx.y * TW + threadIdx.x;

  // ---- stage xyz(+depth) for tile + halo; zero outside image (SAME zero-pad)
  for (int s = tid; s < LH * LW; s += TW * TH) {
    const int ti = s / LW;
    const int tj = s - ti * LW;
    const int gi = i0 - 2 + ti;
    const int gj = j0 - 2 + tj;
    float4 v = make_float4(0.0f, 0.0f, 0.0f, 0.0f);
    if (gi >= 0 && gi < HH && gj >= 0 && gj < WW) {
      const float dsp = disp[(b * HH + gi) * WW + gj];
      const float dd = (float)WW * fmaxf(dsp, 1e-6f);
      const float depth = fxb / dd;
      // grid*depth first (matches ref order), then K_inv matvec
      const float gx = (float)gj * depth;
      const float gy = (float)gi * depth;
      const float gz = depth;
      v.x = Ki00 * gx + Ki01 * gy + Ki02 * gz;
      v.y = Ki10 * gx + Ki11 * gy + Ki12 * gz;
      v.z = Ki20 * gx + Ki21 * gy + Ki22 * gz;
      v.w = depth;
    }
    *(float4*)&tile[ti][tj][0] = v;
  }
  __syncthreads();

  // ---- 5x5 window sums (first + second moments) via ds_read_b128
  float s1x = 0.f, s1y = 0.f, s1z = 0.f;
  float m00 = 0.f, m01 = 0.f, m02 = 0.f, m11 = 0.f, m12 = 0.f, m22 = 0.f;
#pragma unroll
  for (int wi = 0; wi < 5; ++wi) {
#pragma unroll
    for (int wj = 0; wj < 5; ++wj) {
      const float4 v = *(const float4*)&tile[threadIdx.y + wi][threadIdx.x + wj][0];
      s1x += v.x; s1y += v.y; s1z += v.z;
      m00 += v.x * v.x; m01 += v.x * v.y; m02 += v.x * v.z;
      m11 += v.y * v.y; m12 += v.y * v.z; m22 += v.z * v.z;
    }
  }

  const int gi = i0 + threadIdx.y;
  const int gj = j0 + threadIdx.x;
  // valid-element count of the clipped 5x5 window (SAME avg-pool divisor)
  const int ch = min(gi + 2, HH - 1) - max(gi - 2, 0) + 1;
  const int cw = min(gj + 2, WW - 1) - max(gj - 2, 0) + 1;
  const float cnt = (float)(ch * cw);

  const float Px = s1x / cnt, Py = s1y / cnt, Pz = s1z / cnt;
  float a00 = m00 / cnt - Px * Px;
  float a01 = m01 / cnt - Px * Py;
  float a02 = m02 / cnt - Px * Pz;
  float a11 = m11 / cnt - Py * Py;
  float a12 = m12 / cnt - Py * Pz;
  float a22 = m22 / cnt - Pz * Pz;

  float Amax = fmaxf(fabsf(a00), fabsf(a11));
  Amax = fmaxf(Amax, fabsf(a22));
  Amax = fmaxf(Amax, fabsf(a01));
  Amax = fmaxf(Amax, fabsf(a02));
  Amax = fmaxf(Amax, fabsf(a12));
  const float eval_zero = (Amax < 1e-6f) ? 1.0f : 0.0f;
  const float Am = fmaxf(Amax, 1e-6f);
  a00 /= Am; a01 /= Am; a02 /= Am; a11 /= Am; a12 /= Am; a22 /= Am;

  const float nrm = a01 * a01 + a02 * a02 + a12 * a12;
  const float q = (a00 + a11 + a22) / 3.0f;
  const float b00 = a00 - q, b11 = a11 - q, b22 = a22 - q;
  const float p = sqrtf((b00 * b00 + b11 * b11 + b22 * b22 + 2.0f * nrm) / 6.0f);
  const float eig_triple = ((p < 1e-6f) ? 1.0f : 0.0f) * (1.0f - eval_zero);
  const float c00 = b11 * b22 - a12 * a12;
  const float c01 = a01 * b22 - a12 * a02;
  const float c02 = a01 * a12 - b11 * a02;
  const float pm = fmaxf(p, 1e-6f);
  const float det = (b00 * c00 - a01 * c01 + a02 * c02) / (pm * pm * pm);
  const float half_det = fminf(fmaxf(0.5f * det, -1.0f), 1.0f);
  const float angle = acosf(half_det) / 3.0f;
  const float beta2 = cosf(angle) * 2.0f;
  const float beta0 = cosf(angle + 2.0943951023931953f) * 2.0f;  // + 2*pi/3
  const float beta1 = -(beta0 + beta2);
  float e0 = q + p * beta0;
  float e1 = q + p * beta1;
  float e2 = q + p * beta2;
  const float wsel = (1.0f - eval_zero) * (1.0f - eig_triple);
  e0 = eig_triple * q + wsel * e0;
  e1 = eig_triple * q + wsel * e1;
  e2 = eig_triple * q + wsel * e2;

  const float denom = sqrtf(fmaxf((e0 - e1) * (e0 - e2), 0.0f));
  const float evec_zero = (denom < 1e-6f) ? 1.0f : 0.0f;
  const float ny_num =
      sqrtf(fmaxf(e0 * e0 - (a00 + a22) * e0 + (a00 * a22 - a02 * a02), 0.0f));
  const float ny = fminf(fmaxf(ny_num / fmaxf(denom, 1e-6f), 0.0f), 1.0f);
  const float plane_xz = (1.0f - evec_zero) * ny;

  const float yc = tile[threadIdx.y + 2][threadIdx.x + 2][1];
  const float depth_c = tile[threadIdx.y + 2][threadIdx.x + 2][3];
  const float cond1 = (yc > 0.3f) ? 1.0f : 0.0f;
  const float cond2 = (plane_xz > 0.85f) ? 1.0f : 0.0f;

  const int idx = (b * HH + gi) * WW + gj;
  out_depth[idx] = depth_c;
  out_mask[idx] = cond1 * cond2;
}

extern "C" void kernel_launch(void* const* d_in, const int* in_sizes, int n_in,
                              void* d_out, int out_size, void* d_ws, size_t ws_size,
                              hipStream_t stream) {
  const float* disp = (const float*)d_in[0];
  const float* K0 = (const float*)d_in[1];
  const float* baseline = (const float*)d_in[2];
  const int* h0 = (const int*)d_in[3];
  const int* w0 = (const int*)d_in[4];

  float* cst = (float*)d_ws;  // 8 * 12 floats = 384 B
  float* out_depth = (float*)d_out;
  float* out_mask = out_depth + (size_t)BATCH * HH * WW;

  prep_kernel<<<1, BATCH, 0, stream>>>(K0, baseline, h0, w0, cst);

  dim3 block(TW, TH);
  dim3 grid(WW / TW, HH / TH, BATCH);
  tmap_fused<<<grid, block, 0, stream>>>(disp, cst, out_depth, out_mask);
}

// Round 3
// 119.956 us; speedup vs baseline: 1.2738x; 1.2738x over previous
//
#include <hip/hip_runtime.h>

// Problem constants (from setup_inputs): disp [8,384,1280,1] f32
#define BATCH 8
#define HH 384
#define WW 1280
#define TW 32           // tile width  (threads x)
#define TH 8            // tile height (threads y)
#define LW (TW + 4)     // 36: tile + 2-halo each side
#define LH (TH + 4)     // 12

// ---------------------------------------------------------------------------
// Per-batch prep: K1 = K_scale @ K0, K1^{-1} (double adjugate), fxb = K1[0,0]*b
// ---------------------------------------------------------------------------
__global__ void prep_kernel(const float* __restrict__ K0,
                            const float* __restrict__ baseline,
                            const int* __restrict__ h0p,
                            const int* __restrict__ w0p,
                            float* __restrict__ cst) {
  int b = threadIdx.x;
  if (b >= BATCH) return;
  float w0 = (float)w0p[0];
  float h0 = (float)h0p[0];
  float rw = (float)WW / w0;
  float rh = (float)HH / h0;
  float s02 = 0.5f * (rw - 1.0f);
  float s12 = 0.5f * (rh - 1.0f);
  const float* K = K0 + b * 9;
  float k0 = rw * K[0] + s02 * K[6];
  float k1 = rw * K[1] + s02 * K[7];
  float k2 = rw * K[2] + s02 * K[8];
  float k3 = rh * K[3] + s12 * K[6];
  float k4 = rh * K[4] + s12 * K[7];
  float k5 = rh * K[5] + s12 * K[8];
  float k6 = K[6], k7 = K[7], k8 = K[8];
  double a = k0, bb = k1, c = k2, d = k3, e = k4, f = k5, g = k6, h = k7, i = k8;
  double cA = e * i - f * h;
  double cB = -(d * i - f * g);
  double cC = d * h - e * g;
  double det = a * cA + bb * cB + c * cC;
  double idet = 1.0 / det;
  float* o = cst + b * 12;
  o[0] = (float)(cA * idet);
  o[1] = (float)(-(bb * i - c * h) * idet);
  o[2] = (float)((bb * f - c * e) * idet);
  o[3] = (float)(cB * idet);
  o[4] = (float)((a * i - c * g) * idet);
  o[5] = (float)(-(a * f - c * d) * idet);
  o[6] = (float)(cC * idet);
  o[7] = (float)(-(a * h - bb * g) * idet);
  o[8] = (float)((a * e - bb * d) * idet);
  o[9] = k0 * baseline[b];
}

// ---------------------------------------------------------------------------
// Fused kernel, separable 5x5 window:
//   stage 1: xyz(+depth) tile in LDS (zero-pad outside image)
//   stage 2: vertical 5-sums of the 9 moment channels -> LDS
//   stage 3: horizontal 5-sums + eigen epilogue (reciprocal-mult divides)
// ---------------------------------------------------------------------------
__global__ __launch_bounds__(256) void tmap_fused(
    const float* __restrict__ disp,
    const float* __restrict__ cst,
    float* __restrict__ out_depth,
    float* __restrict__ out_mask) {
  __shared__ float4 tile[LH][LW];   // x, y, z, depth            (6.9 KB)
  __shared__ float4 vs0[TH][LW];    // sx, sy, sz, sxx           (4.6 KB)
  __shared__ float4 vs1[TH][LW];    // sxy, sxz, syy, syz        (4.6 KB)
  __shared__ float  vs2[TH][LW];    // szz                       (1.2 KB)

  const int b = blockIdx.z;
  const float* C = cst + b * 12;
  const float Ki00 = C[0], Ki01 = C[1], Ki02 = C[2];
  const float Ki10 = C[3], Ki11 = C[4], Ki12 = C[5];
  const float Ki20 = C[6], Ki21 = C[7], Ki22 = C[8];
  const float fxb = C[9];

  const int j0 = blockIdx.x * TW;
  const int i0 = blockIdx.y * TH;
  const int tid = threadIdx.y * TW + threadIdx.x;

  // ---- stage 1: xyz(+depth) for tile + halo; zero outside image
  for (int s = tid; s < LH * LW; s += TW * TH) {
    const int ti = s / LW;
    const int tj = s - ti * LW;
    const int gi = i0 - 2 + ti;
    const int gj = j0 - 2 + tj;
    float4 v = make_float4(0.0f, 0.0f, 0.0f, 0.0f);
    if (gi >= 0 && gi < HH && gj >= 0 && gj < WW) {
      const float dsp = disp[(b * HH + gi) * WW + gj];
      const float dd = (float)WW * fmaxf(dsp, 1e-6f);
      const float depth = fxb / dd;
      const float gx = (float)gj * depth;
      const float gy = (float)gi * depth;
      const float gz = depth;
      v.x = Ki00 * gx + Ki01 * gy + Ki02 * gz;
      v.y = Ki10 * gx + Ki11 * gy + Ki12 * gz;
      v.z = Ki20 * gx + Ki21 * gy + Ki22 * gz;
      v.w = depth;
    }
    tile[ti][tj] = v;
  }
  __syncthreads();

  // ---- stage 2: vertical 5-sums at TH x LW positions
  for (int s = tid; s < TH * LW; s += TW * TH) {
    const int ti = s / LW;
    const int tj = s - ti * LW;
    float sx = 0.f, sy = 0.f, sz = 0.f;
    float sxx = 0.f, sxy = 0.f, sxz = 0.f, syy = 0.f, syz = 0.f, szz = 0.f;
#pragma unroll
    for (int k = 0; k < 5; ++k) {
      const float4 v = tile[ti + k][tj];
      sx += v.x; sy += v.y; sz += v.z;
      sxx = fmaf(v.x, v.x, sxx);
      sxy = fmaf(v.x, v.y, sxy);
      sxz = fmaf(v.x, v.z, sxz);
      syy = fmaf(v.y, v.y, syy);
      syz = fmaf(v.y, v.z, syz);
      szz = fmaf(v.z, v.z, szz);
    }
    vs0[ti][tj] = make_float4(sx, sy, sz, sxx);
    vs1[ti][tj] = make_float4(sxy, sxz, syy, syz);
    vs2[ti][tj] = szz;
  }
  __syncthreads();

  // ---- stage 3: horizontal 5-sums
  float s1x = 0.f, s1y = 0.f, s1z = 0.f;
  float m00 = 0.f, m01 = 0.f, m02 = 0.f, m11 = 0.f, m12 = 0.f, m22 = 0.f;
#pragma unroll
  for (int w = 0; w < 5; ++w) {
    const float4 va = vs0[threadIdx.y][threadIdx.x + w];
    const float4 vb = vs1[threadIdx.y][threadIdx.x + w];
    const float vc = vs2[threadIdx.y][threadIdx.x + w];
    s1x += va.x; s1y += va.y; s1z += va.z; m00 += va.w;
    m01 += vb.x; m02 += vb.y; m11 += vb.z; m12 += vb.w;
    m22 += vc;
  }

  const int gi = i0 + threadIdx.y;
  const int gj = j0 + threadIdx.x;
  const int ch = min(gi + 2, HH - 1) - max(gi - 2, 0) + 1;
  const int cw = min(gj + 2, WW - 1) - max(gj - 2, 0) + 1;
  const float cnt = (float)(ch * cw);
  const float rcnt = 1.0f / cnt;

  const float Px = s1x * rcnt, Py = s1y * rcnt, Pz = s1z * rcnt;
  float a00 = m00 * rcnt - Px * Px;
  float a01 = m01 * rcnt - Px * Py;
  float a02 = m02 * rcnt - Px * Pz;
  float a11 = m11 * rcnt - Py * Py;
  float a12 = m12 * rcnt - Py * Pz;
  float a22 = m22 * rcnt - Pz * Pz;

  float Amax = fmaxf(fabsf(a00), fabsf(a11));
  Amax = fmaxf(Amax, fabsf(a22));
  Amax = fmaxf(Amax, fabsf(a01));
  Amax = fmaxf(Amax, fabsf(a02));
  Amax = fmaxf(Amax, fabsf(a12));
  const float eval_zero = (Amax < 1e-6f) ? 1.0f : 0.0f;
  const float rAm = 1.0f / fmaxf(Amax, 1e-6f);
  a00 *= rAm; a01 *= rAm; a02 *= rAm; a11 *= rAm; a12 *= rAm; a22 *= rAm;

  const float nrm = a01 * a01 + a02 * a02 + a12 * a12;
  const float q = (a00 + a11 + a22) * (1.0f / 3.0f);
  const float b00 = a00 - q, b11 = a11 - q, b22 = a22 - q;
  const float p = sqrtf((b00 * b00 + b11 * b11 + b22 * b22 + 2.0f * nrm) * (1.0f / 6.0f));
  const float eig_triple = ((p < 1e-6f) ? 1.0f : 0.0f) * (1.0f - eval_zero);
  const float c00 = b11 * b22 - a12 * a12;
  const float c01 = a01 * b22 - a12 * a02;
  const float c02 = a01 * a12 - b11 * a02;
  const float rpm = 1.0f / fmaxf(p, 1e-6f);
  const float det = (b00 * c00 - a01 * c01 + a02 * c02) * (rpm * rpm * rpm);
  const float half_det = fminf(fmaxf(0.5f * det, -1.0f), 1.0f);
  const float angle = acosf(half_det) * (1.0f / 3.0f);
  const float beta2 = cosf(angle) * 2.0f;
  const float beta0 = cosf(angle + 2.0943951023931953f) * 2.0f;  // + 2*pi/3
  const float beta1 = -(beta0 + beta2);
  float e0 = q + p * beta0;
  float e1 = q + p * beta1;
  float e2 = q + p * beta2;
  const float wsel = (1.0f - eval_zero) * (1.0f - eig_triple);
  e0 = eig_triple * q + wsel * e0;
  e1 = eig_triple * q + wsel * e1;
  e2 = eig_triple * q + wsel * e2;

  const float denom = sqrtf(fmaxf((e0 - e1) * (e0 - e2), 0.0f));
  const float evec_zero = (denom < 1e-6f) ? 1.0f : 0.0f;
  const float ny_num =
      sqrtf(fmaxf(e0 * e0 - (a00 + a22) * e0 + (a00 * a22 - a02 * a02), 0.0f));
  const float ny = fminf(fmaxf(ny_num / fmaxf(denom, 1e-6f), 0.0f), 1.0f);
  const float plane_xz = (1.0f - evec_zero) * ny;

  const float4 ctr = tile[threadIdx.y + 2][threadIdx.x + 2];
  const float cond1 = (ctr.y > 0.3f) ? 1.0f : 0.0f;
  const float cond2 = (plane_xz > 0.85f) ? 1.0f : 0.0f;

  const int idx = (b * HH + gi) * WW + gj;
  out_depth[idx] = ctr.w;
  out_mask[idx] = cond1 * cond2;
}

extern "C" void kernel_launch(void* const* d_in, const int* in_sizes, int n_in,
                              void* d_out, int out_size, void* d_ws, size_t ws_size,
                              hipStream_t stream) {
  const float* disp = (const float*)d_in[0];
  const float* K0 = (const float*)d_in[1];
  const float* baseline = (const float*)d_in[2];
  const int* h0 = (const int*)d_in[3];
  const int* w0 = (const int*)d_in[4];

  float* cst = (float*)d_ws;  // 8 * 12 floats = 384 B
  float* out_depth = (float*)d_out;
  float* out_mask = out_depth + (size_t)BATCH * HH * WW;

  prep_kernel<<<1, BATCH, 0, stream>>>(K0, baseline, h0, w0, cst);

  dim3 block(TW, TH);
  dim3 grid(WW / TW, HH / TH, BATCH);
  tmap_fused<<<grid, block, 0, stream>>>(disp, cst, out_depth, out_mask);
}

// Round 5
// 116.773 us; speedup vs baseline: 1.3085x; 1.0273x over previous
//
#include <hip/hip_runtime.h>

// Problem constants (from setup_inputs): disp [8,384,1280,1] f32
#define BATCH 8
#define HH 384
#define WW 1280
#define TW 32           // tile width  (threads x)
#define TH 8            // tile height (threads y)
#define LW (TW + 4)     // 36: tile + 2-halo each side
#define LH (TH + 4)     // 12

// Fast-math helpers (mask-path only; depth output keeps IEEE div).
__device__ __forceinline__ float fast_rcp(float x) {
  float r = __builtin_amdgcn_rcpf(x);
  return fmaf(r, fmaf(-x, r, 1.0f), r);  // 1 Newton step, ~0.5 ulp
}
__device__ __forceinline__ float fast_sqrt(float x) {
  return __builtin_amdgcn_sqrtf(x);      // v_sqrt_f32, ~1 ulp
}
__device__ __forceinline__ float cos_rev(float r) {  // cos(2*pi*r)
  float d;
  asm("v_cos_f32 %0, %1" : "=v"(d) : "v"(r));
  return d;
}

// ---------------------------------------------------------------------------
// Per-batch prep: K1 = K_scale @ K0, K1^{-1} (double adjugate), fxb = K1[0,0]*b
// ---------------------------------------------------------------------------
__global__ void prep_kernel(const float* __restrict__ K0,
                            const float* __restrict__ baseline,
                            const int* __restrict__ h0p,
                            const int* __restrict__ w0p,
                            float* __restrict__ cst) {
  int b = threadIdx.x;
  if (b >= BATCH) return;
  float w0 = (float)w0p[0];
  float h0 = (float)h0p[0];
  float rw = (float)WW / w0;
  float rh = (float)HH / h0;
  float s02 = 0.5f * (rw - 1.0f);
  float s12 = 0.5f * (rh - 1.0f);
  const float* K = K0 + b * 9;
  float k0 = rw * K[0] + s02 * K[6];
  float k1 = rw * K[1] + s02 * K[7];
  float k2 = rw * K[2] + s02 * K[8];
  float k3 = rh * K[3] + s12 * K[6];
  float k4 = rh * K[4] + s12 * K[7];
  float k5 = rh * K[5] + s12 * K[8];
  float k6 = K[6], k7 = K[7], k8 = K[8];
  double a = k0, bb = k1, c = k2, d = k3, e = k4, f = k5, g = k6, h = k7, i = k8;
  double cA = e * i - f * h;
  double cB = -(d * i - f * g);
  double cC = d * h - e * g;
  double det = a * cA + bb * cB + c * cC;
  double idet = 1.0 / det;
  float* o = cst + b * 12;
  o[0] = (float)(cA * idet);
  o[1] = (float)(-(bb * i - c * h) * idet);
  o[2] = (float)((bb * f - c * e) * idet);
  o[3] = (float)(cB * idet);
  o[4] = (float)((a * i - c * g) * idet);
  o[5] = (float)(-(a * f - c * d) * idet);
  o[6] = (float)(cC * idet);
  o[7] = (float)(-(a * h - bb * g) * idet);
  o[8] = (float)((a * e - bb * d) * idet);
  o[9] = k0 * baseline[b];
}

// ---------------------------------------------------------------------------
// Fused kernel, separable 5x5 window:
//   stage 1: xyz(+depth) tile in LDS (zero-pad outside image)
//   stage 2: vertical 5-sums of the 9 moment channels -> LDS
//   stage 3: horizontal 5-sums + eigen epilogue (HW trans, rcp+NR divides)
// ---------------------------------------------------------------------------
__global__ __launch_bounds__(256) void tmap_fused(
    const float* __restrict__ disp,
    const float* __restrict__ cst,
    float* __restrict__ out_depth,
    float* __restrict__ out_mask) {
  __shared__ float4 tile[LH][LW];   // x, y, z, depth            (6.9 KB)
  __shared__ float4 vs0[TH][LW];    // sx, sy, sz, sxx           (4.6 KB)
  __shared__ float4 vs1[TH][LW];    // sxy, sxz, syy, syz        (4.6 KB)
  __shared__ float  vs2[TH][LW];    // szz                       (1.2 KB)

  const int b = blockIdx.z;
  const float* C = cst + b * 12;
  const float Ki00 = C[0], Ki01 = C[1], Ki02 = C[2];
  const float Ki10 = C[3], Ki11 = C[4], Ki12 = C[5];
  const float Ki20 = C[6], Ki21 = C[7], Ki22 = C[8];
  const float fxb = C[9];

  const int j0 = blockIdx.x * TW;
  const int i0 = blockIdx.y * TH;
  const int tid = threadIdx.y * TW + threadIdx.x;

  // ---- stage 1: xyz(+depth) for tile + halo; zero outside image
  for (int s = tid; s < LH * LW; s += TW * TH) {
    const int ti = s / LW;
    const int tj = s - ti * LW;
    const int gi = i0 - 2 + ti;
    const int gj = j0 - 2 + tj;
    float4 v = make_float4(0.0f, 0.0f, 0.0f, 0.0f);
    if (gi >= 0 && gi < HH && gj >= 0 && gj < WW) {
      const float dsp = disp[(b * HH + gi) * WW + gj];
      const float dd = (float)WW * fmaxf(dsp, 1e-6f);
      const float depth = fxb / dd;           // IEEE: feeds depth output
      const float jf = (float)gj;
      const float iff = (float)gi;
      v.x = depth * fmaf(Ki00, jf, fmaf(Ki01, iff, Ki02));
      v.y = depth * fmaf(Ki10, jf, fmaf(Ki11, iff, Ki12));
      v.z = depth * fmaf(Ki20, jf, fmaf(Ki21, iff, Ki22));
      v.w = depth;
    }
    tile[ti][tj] = v;
  }
  __syncthreads();

  // ---- stage 2: vertical 5-sums at TH x LW positions
  for (int s = tid; s < TH * LW; s += TW * TH) {
    const int ti = s / LW;
    const int tj = s - ti * LW;
    float sx = 0.f, sy = 0.f, sz = 0.f;
    float sxx = 0.f, sxy = 0.f, sxz = 0.f, syy = 0.f, syz = 0.f, szz = 0.f;
#pragma unroll
    for (int k = 0; k < 5; ++k) {
      const float4 v = tile[ti + k][tj];
      sx += v.x; sy += v.y; sz += v.z;
      sxx = fmaf(v.x, v.x, sxx);
      sxy = fmaf(v.x, v.y, sxy);
      sxz = fmaf(v.x, v.z, sxz);
      syy = fmaf(v.y, v.y, syy);
      syz = fmaf(v.y, v.z, syz);
      szz = fmaf(v.z, v.z, szz);
    }
    vs0[ti][tj] = make_float4(sx, sy, sz, sxx);
    vs1[ti][tj] = make_float4(sxy, sxz, syy, syz);
    vs2[ti][tj] = szz;
  }
  __syncthreads();

  // ---- stage 3: horizontal 5-sums
  float s1x = 0.f, s1y = 0.f, s1z = 0.f;
  float m00 = 0.f, m01 = 0.f, m02 = 0.f, m11 = 0.f, m12 = 0.f, m22 = 0.f;
#pragma unroll
  for (int w = 0; w < 5; ++w) {
    const float4 va = vs0[threadIdx.y][threadIdx.x + w];
    const float4 vb = vs1[threadIdx.y][threadIdx.x + w];
    const float vc = vs2[threadIdx.y][threadIdx.x + w];
    s1x += va.x; s1y += va.y; s1z += va.z; m00 += va.w;
    m01 += vb.x; m02 += vb.y; m11 += vb.z; m12 += vb.w;
    m22 += vc;
  }

  const int gi = i0 + threadIdx.y;
  const int gj = j0 + threadIdx.x;
  const int ch = min(gi + 2, HH - 1) - max(gi - 2, 0) + 1;
  const int cw = min(gj + 2, WW - 1) - max(gj - 2, 0) + 1;
  const float cnt = (float)(ch * cw);
  const float rcnt = fast_rcp(cnt);

  const float Px = s1x * rcnt, Py = s1y * rcnt, Pz = s1z * rcnt;
  float a00 = m00 * rcnt - Px * Px;
  float a01 = m01 * rcnt - Px * Py;
  float a02 = m02 * rcnt - Px * Pz;
  float a11 = m11 * rcnt - Py * Py;
  float a12 = m12 * rcnt - Py * Pz;
  float a22 = m22 * rcnt - Pz * Pz;

  float Amax = fmaxf(fabsf(a00), fabsf(a11));
  Amax = fmaxf(Amax, fabsf(a22));
  Amax = fmaxf(Amax, fabsf(a01));
  Amax = fmaxf(Amax, fabsf(a02));
  Amax = fmaxf(Amax, fabsf(a12));
  const float eval_zero = (Amax < 1e-6f) ? 1.0f : 0.0f;
  const float rAm = fast_rcp(fmaxf(Amax, 1e-6f));
  a00 *= rAm; a01 *= rAm; a02 *= rAm; a11 *= rAm; a12 *= rAm; a22 *= rAm;

  const float nrm = a01 * a01 + a02 * a02 + a12 * a12;
  const float q = (a00 + a11 + a22) * (1.0f / 3.0f);
  const float b00 = a00 - q, b11 = a11 - q, b22 = a22 - q;
  const float p =
      fast_sqrt((b00 * b00 + b11 * b11 + b22 * b22 + 2.0f * nrm) * (1.0f / 6.0f));
  const float eig_triple = ((p < 1e-6f) ? 1.0f : 0.0f) * (1.0f - eval_zero);
  const float c00 = b11 * b22 - a12 * a12;
  const float c01 = a01 * b22 - a12 * a02;
  const float c02 = a01 * a12 - b11 * a02;
  const float rpm = fast_rcp(fmaxf(p, 1e-6f));
  const float det = (b00 * c00 - a01 * c01 + a02 * c02) * (rpm * rpm * rpm);
  const float half_det = fminf(fmaxf(0.5f * det, -1.0f), 1.0f);
  // angle = acos(half_det)/3; betas via HW v_cos (input in revolutions)
  const float t = acosf(half_det);
  const float rev = t * 0.05305164769729845f;  // 1/(6*pi)
  const float beta2 = 2.0f * cos_rev(rev);                    // 2*cos(t/3)
  const float beta0 = 2.0f * cos_rev(rev + (1.0f / 3.0f));    // 2*cos(t/3+2pi/3)
  const float beta1 = -(beta0 + beta2);
  float e0 = q + p * beta0;
  float e1 = q + p * beta1;
  float e2 = q + p * beta2;
  const float wsel = (1.0f - eval_zero) * (1.0f - eig_triple);
  e0 = eig_triple * q + wsel * e0;
  e1 = eig_triple * q + wsel * e1;
  e2 = eig_triple * q + wsel * e2;

  const float denom = fast_sqrt(fmaxf((e0 - e1) * (e0 - e2), 0.0f));
  const float evec_zero = (denom < 1e-6f) ? 1.0f : 0.0f;
  const float ny_num =
      fast_sqrt(fmaxf(e0 * e0 - (a00 + a22) * e0 + (a00 * a22 - a02 * a02), 0.0f));
  const float ny =
      fminf(fmaxf(ny_num * fast_rcp(fmaxf(denom, 1e-6f)), 0.0f), 1.0f);
  const float plane_xz = (1.0f - evec_zero) * ny;

  const float4 ctr = tile[threadIdx.y + 2][threadIdx.x + 2];
  const float cond1 = (ctr.y > 0.3f) ? 1.0f : 0.0f;
  const float cond2 = (plane_xz > 0.85f) ? 1.0f : 0.0f;

  const int idx = (b * HH + gi) * WW + gj;
  out_depth[idx] = ctr.w;
  out_mask[idx] = cond1 * cond2;
}

extern "C" void kernel_launch(void* const* d_in, const int* in_sizes, int n_in,
                              void* d_out, int out_size, void* d_ws, size_t ws_size,
                              hipStream_t stream) {
  const float* disp = (const float*)d_in[0];
  const float* K0 = (const float*)d_in[1];
  const float* baseline = (const float*)d_in[2];
  const int* h0 = (const int*)d_in[3];
  const int* w0 = (const int*)d_in[4];

  float* cst = (float*)d_ws;  // 8 * 12 floats = 384 B
  float* out_depth = (float*)d_out;
  float* out_mask = out_depth + (size_t)BATCH * HH * WW;

  prep_kernel<<<1, BATCH, 0, stream>>>(K0, baseline, h0, w0, cst);

  dim3 block(TW, TH);
  dim3 grid(WW / TW, HH / TH, BATCH);
  tmap_fused<<<grid, block, 0, stream>>>(disp, cst, out_depth, out_mask);
}